// Round 7
// baseline (141.607 us; speedup 1.0000x reference)
//
#include <hip/hip_runtime.h>
#include <cstdint>

// VQ-VAE vector quantizer, MI355X (gfx950). Round 7.
// r3-r6 falsified: kernel ~66/45/43/35us invariant to waves/SIMD, ds:MFMA
// ratio, and barrier count. Remaining suspects: ds_read->MFMA dependency,
// serial z-prologue, in-loop eTe loads. Round 7 removes ALL of them by
// swapping MFMA roles:
//  - codebook fp8 = A-operand RESIDENT IN REGISTERS: 8 waves x 128 codes
//    (128 VGPRs each), loaded once from prep's fragment-linear layout.
//  - z streams as B-fragments packed in registers from global (L1-hot: all
//    8 waves of the block read the same 16KB tile). Hot loop: 16 coalesced
//    loads + 8 packs + 64 MFMA (8 indep chains) - NO LDS, NO barriers.
//  - fully fused: per-tile argmin -> LDS; one end barrier; merge across
//    waves, gather emb[idx], write out, loss = zsq + best/1024.
//  - grid 256 x 512thr (8 waves, 1 block/CU); launch_bounds(512,2) -> 256
//    VGPR cap, est ~220 live.

typedef float f32x4 __attribute__((ext_vector_type(4)));
typedef long  l2    __attribute__((ext_vector_type(2)));
typedef _Float16 f16;
typedef f16 f16x8 __attribute__((ext_vector_type(8)));

#define D_DIM 256
#define K_CODES 1024
#define NROWS_TOT 32768

__device__ __forceinline__ long pack_fp8x8(float x0, float x1, float x2, float x3,
                                           float x4, float x5, float x6, float x7) {
    int w0 = __builtin_amdgcn_cvt_pk_fp8_f32(x0, x1, 0, false);
    w0     = __builtin_amdgcn_cvt_pk_fp8_f32(x2, x3, w0, true);
    int w1 = __builtin_amdgcn_cvt_pk_fp8_f32(x4, x5, 0, false);
    w1     = __builtin_amdgcn_cvt_pk_fp8_f32(x6, x7, w1, true);
    int2 p = {w0, w1};
    return __builtin_bit_cast(long, p);
}

// ---- Prep (verified r5/r6): zero loss slot; emb -> fp8 (x1024) in
// fragment-linear order: 16 slices of 64 codes; chunk sp*1024 + ct*256 +
// t*64 + q*16 + m holds k-dims [t*64+q*8,+8) and [t*64+32+q*8,+8) of code
// sp*64+ct*16+m. eTe = 1024*||e||^2 fp32. grid 256 x 256.
__global__ __launch_bounds__(256) void vq_prep(const float* __restrict__ emb,
                                               char* __restrict__ emb8,
                                               float* __restrict__ eTe,
                                               float* __restrict__ loss_slot) {
    const int tid = threadIdx.x, wave = tid >> 6, lane = tid & 63;
    if (blockIdx.x == 0 && tid == 0) *loss_slot = 0.0f;

    if (blockIdx.x < 64) {
        int ch  = blockIdx.x * 256 + tid;     // 16384 chunks
        int sp  = ch >> 10;
        int rem = ch & 1023;
        int ct  = rem >> 8;
        int t   = (rem >> 6) & 3;
        int l   = rem & 63;
        int qq  = l >> 4, mm = l & 15;
        int code = sp * 64 + ct * 16 + mm;
        const float* p = emb + (size_t)code * D_DIM;
        int b0 = t * 64 + qq * 8;
        int b1 = b0 + 32;
        float4 v0 = *(const float4*)(p + b0);
        float4 v1 = *(const float4*)(p + b0 + 4);
        float4 v2 = *(const float4*)(p + b1);
        float4 v3 = *(const float4*)(p + b1 + 4);
        l2 o;
        o.x = pack_fp8x8(v0.x * 1024.f, v0.y * 1024.f, v0.z * 1024.f, v0.w * 1024.f,
                         v1.x * 1024.f, v1.y * 1024.f, v1.z * 1024.f, v1.w * 1024.f);
        o.y = pack_fp8x8(v2.x * 1024.f, v2.y * 1024.f, v2.z * 1024.f, v2.w * 1024.f,
                         v3.x * 1024.f, v3.y * 1024.f, v3.z * 1024.f, v3.w * 1024.f);
        *(l2*)(emb8 + (size_t)ch * 16) = o;
    }

    int code = blockIdx.x * 4 + wave;
    float4 v = ((const float4*)(emb + (size_t)code * D_DIM))[lane];
    float s = v.x * v.x + v.y * v.y + v.z * v.z + v.w * v.w;
    #pragma unroll
    for (int off = 32; off >= 1; off >>= 1) s += __shfl_down(s, off);
    if (lane == 0) eTe[code] = 1024.0f * s;
}

// ---- Fused score + gather + loss. grid 256 x 512 thr. --------------------
__global__ __launch_bounds__(512, 2) void vq_fused(const float* __restrict__ z,
                                                   const char* __restrict__ emb8,
                                                   const float* __restrict__ eTe,
                                                   const float* __restrict__ emb,
                                                   float* __restrict__ out,
                                                   float* __restrict__ loss_slot,
                                                   float loss_scale) {
    __shared__ float s_best[8 * 128];
    __shared__ int   s_bidx[8 * 128];
    __shared__ float s_zsq[128];
    __shared__ float s_red[8];

    const int tid  = threadIdx.x;
    const int wave = tid >> 6;        // 0..7 -> owns codes wave*128..+127
    const int lane = tid & 63;
    const int m    = lane & 15;       // A code-row / B z-col / C col (z-row)
    const int q    = lane >> 4;       // k-group / C row-group (code)
    const size_t rowbase = (size_t)blockIdx.x * 128;

    // Codebook A-fragments: 8 ct x 4 t chunk-pairs, resident in registers.
    // cb[ct][t].x covers k [t*64, +32), .y covers [t*64+32, +32) for codes
    // wave*128 + ct*16 + (rows). Lane-linear in the prep layout -> coalesced.
    l2 cb[8][4];
    {
        const l2* src = (const l2*)emb8 + (size_t)wave * 2048;  // 2 slices
        #pragma unroll
        for (int ct = 0; ct < 8; ct++)
            #pragma unroll
            for (int t = 0; t < 4; t++)
                cb[ct][t] = src[(ct >> 2) * 1024 + (ct & 3) * 256 + t * 64 + lane];
    }

    #pragma unroll 1
    for (int t = 0; t < 8; t++) {     // 8 z-tiles of 16 rows
        // B-fragments: z rows rowbase+t*16+m, packed fp8 in registers.
        // zB[c] covers k [c*32, +32): lane holds B[k=q*8+j][n=m].
        const float* ztile = z + (rowbase + t * 16 + m) * D_DIM;
        l2 zB4[4];
        float zq = 0.f;
        #pragma unroll
        for (int c = 0; c < 4; c++) {
            const float* p0 = ztile + (2 * c) * 32 + q * 8;
            const float* p1 = ztile + (2 * c + 1) * 32 + q * 8;
            float4 a0 = *(const float4*)p0;
            float4 a1 = *(const float4*)(p0 + 4);
            float4 b0 = *(const float4*)p1;
            float4 b1 = *(const float4*)(p1 + 4);
            zq += a0.x*a0.x + a0.y*a0.y + a0.z*a0.z + a0.w*a0.w
                + a1.x*a1.x + a1.y*a1.y + a1.z*a1.z + a1.w*a1.w
                + b0.x*b0.x + b0.y*b0.y + b0.z*b0.z + b0.w*b0.w
                + b1.x*b1.x + b1.y*b1.y + b1.z*b1.z + b1.w*b1.w;
            zB4[c].x = pack_fp8x8(a0.x, a0.y, a0.z, a0.w, a1.x, a1.y, a1.z, a1.w);
            zB4[c].y = pack_fp8x8(b0.x, b0.y, b0.z, b0.w, b1.x, b1.y, b1.z, b1.w);
        }

        // 8 independent MFMA chains (one per 16-code subtile), 8 k-steps each.
        f32x4 acc[8];
        #pragma unroll
        for (int ct = 0; ct < 8; ct++) acc[ct] = (f32x4){0.f, 0.f, 0.f, 0.f};
        #pragma unroll
        for (int tt = 0; tt < 4; tt++) {
            #pragma unroll
            for (int ct = 0; ct < 8; ct++)
                acc[ct] = __builtin_amdgcn_mfma_f32_16x16x32_fp8_fp8(cb[ct][tt].x, zB4[tt].x, acc[ct], 0, 0, 0);
            #pragma unroll
            for (int ct = 0; ct < 8; ct++)
                acc[ct] = __builtin_amdgcn_mfma_f32_16x16x32_fp8_fp8(cb[ct][tt].y, zB4[tt].y, acc[ct], 0, 0, 0);
        }

        // Per-lane argmin over this wave's 128 codes for z-row (t*16+m).
        // C layout: acc[ct][r] = score-dot of code wave*128+ct*16+q*4+r.
        float best = __builtin_inff();
        int   bidx = 0;
        #pragma unroll
        for (int ct = 0; ct < 8; ct++) {
            float4 ete4 = *(const float4*)(eTe + wave * 128 + ct * 16 + q * 4);
            int cbase = wave * 128 + ct * 16 + q * 4;
            float e0 = ete4.x, e1 = ete4.y, e2 = ete4.z, e3 = ete4.w;
            float s0 = fmaf(-2.0f, acc[ct][0], e0);
            float s1 = fmaf(-2.0f, acc[ct][1], e1);
            float s2 = fmaf(-2.0f, acc[ct][2], e2);
            float s3 = fmaf(-2.0f, acc[ct][3], e3);
            if (s0 < best) { best = s0; bidx = cbase + 0; }
            if (s1 < best) { best = s1; bidx = cbase + 1; }
            if (s2 < best) { best = s2; bidx = cbase + 2; }
            if (s3 < best) { best = s3; bidx = cbase + 3; }
        }
        // Cross-q reduce (4 q-groups hold different code rows of same z-row).
        #pragma unroll
        for (int off = 16; off <= 32; off <<= 1) {
            float ob = __shfl_xor(best, off);
            int   oi = __shfl_xor(bidx, off);
            if (ob < best || (ob == best && oi < bidx)) { best = ob; bidx = oi; }
        }
        if (q == 0) {
            s_best[wave * 128 + t * 16 + m] = best;
            s_bidx[wave * 128 + t * 16 + m] = bidx;
        }
        if (wave == 0) {     // all waves compute identical zq; wave 0 publishes
            float zrow = zq + __shfl_xor(zq, 16);
            zrow += __shfl_xor(zrow, 32);
            if (q == 0) s_zsq[t * 16 + m] = zrow;
        }
    }
    __syncthreads();

    // Merge 8 waves' candidates per row (wave order = ascending code blocks,
    // strict < keeps lowest index on ties -> np.argmin semantics), gather
    // emb[idx], write out, loss = zsq + best/1024.
    const int row = tid >> 2;       // 0..127
    const int sub = tid & 3;        // 64-dim quarter
    float b  = s_best[row];
    int   bi = s_bidx[row];
    #pragma unroll
    for (int w = 1; w < 8; w++) {
        float ob = s_best[w * 128 + row];
        int   oi = s_bidx[w * 128 + row];
        if (ob < b) { b = ob; bi = oi; }
    }
    const float4* er = (const float4*)(emb + (size_t)bi * D_DIM + sub * 64);
    float4* orow = (float4*)(out + (rowbase + row) * D_DIM + sub * 64);
    #pragma unroll
    for (int i = 0; i < 16; i++) orow[i] = er[i];

    float lsum = (sub == 0) ? (s_zsq[row] + b * (1.0f / 1024.0f)) : 0.f;
    #pragma unroll
    for (int off = 32; off >= 1; off >>= 1) lsum += __shfl_down(lsum, off);
    if (lane == 0) s_red[wave] = lsum;
    __syncthreads();
    if (tid == 0) {
        float tot = 0.f;
        #pragma unroll
        for (int w = 0; w < 8; w++) tot += s_red[w];
        atomicAdd(loss_slot, tot * loss_scale);
    }
}

// ---- Fallback (round-2 structure, verified) — only if ws too small. --------
__global__ __launch_bounds__(256) void vq_prep_fb(const float* __restrict__ emb,
                                                  float* __restrict__ eTe,
                                                  float* __restrict__ loss_slot) {
    if (blockIdx.x == 0 && threadIdx.x == 0) *loss_slot = 0.0f;
    if (!eTe) return;
    int gtid = blockIdx.x * 256 + threadIdx.x;
    int code = gtid >> 6;
    int lane = threadIdx.x & 63;
    if (code >= K_CODES) return;
    float4 v = ((const float4*)(emb + (size_t)code * D_DIM))[lane];
    float s = v.x * v.x + v.y * v.y + v.z * v.z + v.w * v.w;
    #pragma unroll
    for (int off = 32; off >= 1; off >>= 1) s += __shfl_down(s, off);
    if (lane == 0) eTe[code] = s;
}

__global__ __launch_bounds__(128) void vq_main_fb(const float* __restrict__ z,
                                                  const float* __restrict__ emb,
                                                  const float* __restrict__ eTe_g,
                                                  float* __restrict__ out,
                                                  float* __restrict__ loss_slot,
                                                  float loss_scale) {
    __shared__ __align__(16) f16 sE[128 * D_DIM];
    __shared__ float s_ete[128];
    __shared__ int   s_idx2[128];
    __shared__ float s_red2[2];

    const int tid  = threadIdx.x;
    const int wave = tid >> 6;
    const int lane = tid & 63;
    const int m    = lane & 15;
    const int q    = lane >> 4;
    const size_t row0 = (size_t)blockIdx.x * 128 + (size_t)wave * 64;

    f16x8 A[4][8];
    #pragma unroll
    for (int st = 0; st < 4; st++) {
        const float* zr = z + (row0 + st * 16 + m) * D_DIM;
        #pragma unroll
        for (int s = 0; s < 8; s++) {
            const float* p = zr + s * 32 + q * 8;
            float4 v0 = *(const float4*)p;
            float4 v1 = *(const float4*)(p + 4);
            f16x8 a = {(f16)v0.x, (f16)v0.y, (f16)v0.z, (f16)v0.w,
                       (f16)v1.x, (f16)v1.y, (f16)v1.z, (f16)v1.w};
            A[st][s] = a;
        }
    }
    float best[4][4]; int bidx[4][4];
    #pragma unroll
    for (int st = 0; st < 4; st++)
        #pragma unroll
        for (int r = 0; r < 4; r++) { best[st][r] = __builtin_inff(); bidx[st][r] = 0; }

    const f16x8* sE8 = (const f16x8*)sE;
    #pragma unroll 1
    for (int sp = 0; sp < 8; sp++) {
        __syncthreads();
        if (eTe_g) s_ete[tid] = 1024.0f * eTe_g[sp * 128 + tid];
        else {
            const float* p = emb + (size_t)(sp * 128 + tid) * D_DIM;
            float ss = 0.f;
            for (int j = 0; j < D_DIM / 4; j++) {
                float4 v = ((const float4*)p)[j];
                ss += v.x * v.x + v.y * v.y + v.z * v.z + v.w * v.w;
            }
            s_ete[tid] = 1024.0f * ss;
        }
        const float* ebase = emb + (size_t)sp * 128 * D_DIM;
        #pragma unroll 4
        for (int it = 0; it < 32; it++) {
            int ch = it * 128 + tid;
            int cc = ((ch >> 9) << 4) | (ch & 15);
            int gg = (ch >> 4) & 31;
            const float* p = ebase + cc * D_DIM + gg * 8;
            float4 v0 = *(const float4*)p;
            float4 v1 = *(const float4*)(p + 4);
            f16x8 h = {(f16)(v0.x * 1024.f), (f16)(v0.y * 1024.f),
                       (f16)(v0.z * 1024.f), (f16)(v0.w * 1024.f),
                       (f16)(v1.x * 1024.f), (f16)(v1.y * 1024.f),
                       (f16)(v1.z * 1024.f), (f16)(v1.w * 1024.f)};
            *(f16x8*)(sE + (size_t)ch * 8) = h;
        }
        __syncthreads();
        for (int ct = 0; ct < 8; ct++) {
            f32x4 acc[4];
            #pragma unroll
            for (int st = 0; st < 4; st++) acc[st] = (f32x4){0.f, 0.f, 0.f, 0.f};
            #pragma unroll
            for (int s = 0; s < 8; s++) {
                f16x8 bh = sE8[ct * 512 + s * 64 + lane];
                #pragma unroll
                for (int st = 0; st < 4; st++)
                    acc[st] = __builtin_amdgcn_mfma_f32_16x16x32_f16(A[st][s], bh, acc[st], 0, 0, 0);
            }
            int codeL = ct * 16 + m;
            float ete = s_ete[codeL];
            int code  = sp * 128 + codeL;
            #pragma unroll
            for (int st = 0; st < 4; st++)
                #pragma unroll
                for (int r = 0; r < 4; r++) {
                    float sc = fmaf(-2.0f, acc[st][r], ete);
                    if (sc < best[st][r]) { best[st][r] = sc; bidx[st][r] = code; }
                }
        }
    }
    #pragma unroll
    for (int st = 0; st < 4; st++)
        #pragma unroll
        for (int r = 0; r < 4; r++) {
            float b = best[st][r]; int bi = bidx[st][r];
            #pragma unroll
            for (int off = 8; off >= 1; off >>= 1) {
                float ob = __shfl_xor(b, off);
                int   oi = __shfl_xor(bi, off);
                if (ob < b || (ob == b && oi < bi)) { b = ob; bi = oi; }
            }
            if (m == 0) s_idx2[wave * 64 + st * 16 + q * 4 + r] = bi;
        }
    __syncthreads();
    float lsum = 0.f;
    #pragma unroll
    for (int st = 0; st < 4; st++) {
        int rl = wave * 64 + st * 16 + m;
        int idxv = s_idx2[rl];
        const float* er = emb + (size_t)idxv * D_DIM;
        float* orow = out + ((size_t)blockIdx.x * 128 + rl) * D_DIM;
        #pragma unroll
        for (int s = 0; s < 8; s++) {
            int dd = s * 32 + q * 8;
            float4 e0 = *(const float4*)(er + dd);
            float4 e1 = *(const float4*)(er + dd + 4);
            *(float4*)(orow + dd)     = e0;
            *(float4*)(orow + dd + 4) = e1;
            f16x8 a = A[st][s];
            float d0 = e0.x - (float)a[0], d1 = e0.y - (float)a[1];
            float d2 = e0.z - (float)a[2], d3 = e0.w - (float)a[3];
            float d4 = e1.x - (float)a[4], d5 = e1.y - (float)a[5];
            float d6 = e1.z - (float)a[6], d7 = e1.w - (float)a[7];
            lsum += d0*d0 + d1*d1 + d2*d2 + d3*d3 + d4*d4 + d5*d5 + d6*d6 + d7*d7;
        }
    }
    #pragma unroll
    for (int off = 32; off >= 1; off >>= 1) lsum += __shfl_down(lsum, off);
    if (lane == 0) s_red2[wave] = lsum;
    __syncthreads();
    if (tid == 0) atomicAdd(loss_slot, (s_red2[0] + s_red2[1]) * loss_scale);
}

extern "C" void kernel_launch(void* const* d_in, const int* in_sizes, int n_in,
                              void* d_out, int out_size, void* d_ws, size_t ws_size,
                              hipStream_t stream) {
    const float* z   = (const float*)d_in[0];
    const float* emb = (const float*)d_in[1];
    float* out = (float*)d_out;
    float* loss_slot = out + (size_t)in_sizes[0];
    float loss_scale = 1.25f / (float)in_sizes[0];

    const size_t emb8_bytes = (size_t)K_CODES * D_DIM;  // 256 KB
    const size_t need = emb8_bytes + K_CODES * sizeof(float);

    if (ws_size >= need) {
        char*  emb8 = (char*)d_ws;
        float* eTe  = (float*)((char*)d_ws + emb8_bytes);
        vq_prep<<<256, 256, 0, stream>>>(emb, emb8, eTe, loss_slot);
        vq_fused<<<NROWS_TOT / 128, 512, 0, stream>>>(z, emb8, eTe, emb, out,
                                                      loss_slot, loss_scale);
    } else {
        float* eTe = (ws_size >= K_CODES * sizeof(float)) ? (float*)d_ws : nullptr;
        vq_prep_fb<<<K_CODES / 4, 256, 0, stream>>>(emb, eTe, loss_slot);
        vq_main_fb<<<NROWS_TOT / 128, 128, 0, stream>>>(z, emb, eTe, out, loss_slot, loss_scale);
    }
}

// Round 9
// 123.677 us; speedup vs baseline: 1.1450x; 1.1450x over previous
//
#include <hip/hip_runtime.h>
#include <cstdint>

// VQ-VAE vector quantizer, MI355X (gfx950). Round 9 (= r8 with compile fix).
// r8 failed compile: __builtin_nontemporal_* rejects HIP_vector_type<float,4>*.
// Fix: clang ext_vector float4 alias (f4) for NT-accessed pointers.
// Structure = r5 (verified best, total 116.2us, absmax 1.95e-3) + NT hints:
//  - NT stores for out (33.5 MB, never re-read): keeps L2 for emb8/eTe/z.
//  - NT loads for z (read exactly once per launch).

typedef float f32x4 __attribute__((ext_vector_type(4)));
typedef float f4    __attribute__((ext_vector_type(4)));   // NT-compatible
typedef long  l2    __attribute__((ext_vector_type(2)));
typedef _Float16 f16;
typedef f16 f16x8 __attribute__((ext_vector_type(8)));

#define D_DIM 256
#define K_CODES 1024
#define BM 64                       // rows per block
#define SLICE_CODES 64
#define SLICE_BYTES (SLICE_CODES * D_DIM)   // 16384 (fp8)
#define NSLICE_G 8                  // slices per code-group (8 x 64 = 512 codes)

__device__ __forceinline__ void async_copy16(const void* g, void* l) {
    __builtin_amdgcn_global_load_lds(
        (const __attribute__((address_space(1))) void*)g,
        (__attribute__((address_space(3))) void*)l, 16, 0, 0);
}

__device__ __forceinline__ long pack_fp8x8(float x0, float x1, float x2, float x3,
                                           float x4, float x5, float x6, float x7) {
    int w0 = __builtin_amdgcn_cvt_pk_fp8_f32(x0, x1, 0, false);
    w0     = __builtin_amdgcn_cvt_pk_fp8_f32(x2, x3, w0, true);
    int w1 = __builtin_amdgcn_cvt_pk_fp8_f32(x4, x5, 0, false);
    w1     = __builtin_amdgcn_cvt_pk_fp8_f32(x6, x7, w1, true);
    int2 p = {w0, w1};
    return __builtin_bit_cast(long, p);
}

// ---- Prep (verified r5-r7): zero loss slot; emb -> fp8 (x1024) in
// fragment-slice-linear order (16 slices of 64 codes; chunk sp*1024 +
// ct*256 + t*64 + q*16 + m holds k-dims [t*64+q*8,+8) and [t*64+32+q*8,+8)
// of code sp*64+ct*16+m); eTe = 1024*||e||^2 fp32. grid 256 x 256.
__global__ __launch_bounds__(256) void vq_prep(const float* __restrict__ emb,
                                               char* __restrict__ emb8,
                                               float* __restrict__ eTe,
                                               float* __restrict__ loss_slot) {
    const int tid = threadIdx.x, wave = tid >> 6, lane = tid & 63;
    if (blockIdx.x == 0 && tid == 0) *loss_slot = 0.0f;

    if (blockIdx.x < 64) {
        int ch  = blockIdx.x * 256 + tid;     // 16384 chunks
        int sp  = ch >> 10;
        int rem = ch & 1023;
        int ct  = rem >> 8;
        int t   = (rem >> 6) & 3;
        int l   = rem & 63;
        int qq  = l >> 4, mm = l & 15;
        int code = sp * 64 + ct * 16 + mm;
        const float* p = emb + (size_t)code * D_DIM;
        int b0 = t * 64 + qq * 8;
        int b1 = b0 + 32;
        float4 v0 = *(const float4*)(p + b0);
        float4 v1 = *(const float4*)(p + b0 + 4);
        float4 v2 = *(const float4*)(p + b1);
        float4 v3 = *(const float4*)(p + b1 + 4);
        l2 o;
        o.x = pack_fp8x8(v0.x * 1024.f, v0.y * 1024.f, v0.z * 1024.f, v0.w * 1024.f,
                         v1.x * 1024.f, v1.y * 1024.f, v1.z * 1024.f, v1.w * 1024.f);
        o.y = pack_fp8x8(v2.x * 1024.f, v2.y * 1024.f, v2.z * 1024.f, v2.w * 1024.f,
                         v3.x * 1024.f, v3.y * 1024.f, v3.z * 1024.f, v3.w * 1024.f);
        *(l2*)(emb8 + (size_t)ch * 16) = o;
    }

    int code = blockIdx.x * 4 + wave;
    float4 v = ((const float4*)(emb + (size_t)code * D_DIM))[lane];
    float s = v.x * v.x + v.y * v.y + v.z * v.z + v.w * v.w;
    #pragma unroll
    for (int off = 32; off >= 1; off >>= 1) s += __shfl_down(s, off);
    if (lane == 0) eTe[code] = 1024.0f * s;
}

// ---- Main kernel (r5 structure, verified): 512 thr, waves 0-3 score codes
// 0-511, waves 4-7 codes 512-1023 on the same 64 rows; two independent dbuf
// streams (2 groups x 2 x 16 KB LDS); argmin merged in LDS; fused epilogue.
__global__ __launch_bounds__(512, 4) void vq_main(const float* __restrict__ z,
                                                  const char* __restrict__ emb8,
                                                  const float* __restrict__ eTe,
                                                  const float* __restrict__ emb,
                                                  float* __restrict__ out,
                                                  float* __restrict__ loss_slot,
                                                  float loss_scale) {
    __shared__ __align__(16) char sB[2][2][SLICE_BYTES];   // [group][dbuf] 64 KB
    __shared__ float s_best[2][BM];
    __shared__ int   s_bidx[2][BM];
    __shared__ int   s_idx[BM];
    __shared__ float s_fin[BM];
    __shared__ float s_red[4];

    const int tid  = threadIdx.x;
    const int wave = tid >> 6;        // 0..7
    const int g    = tid >> 8;        // code-group 0/1
    const int wl   = wave & 3;        // wave within group -> row strip
    const int lane = tid & 63;
    const int m    = lane & 15;       // A row / B col (code) / C col
    const int q    = lane >> 4;       // k-group / C row-group
    const int tidl = tid & 255;       // thread within group

    // Stage this group's slice 0 (async) before the A load.
    {
        const char* src = emb8 + (size_t)(g * NSLICE_G) * SLICE_BYTES;
        char* dst = sB[g][0];
        #pragma unroll
        for (int ii = 0; ii < 4; ii++) {
            int ch = ii * 256 + tidl;
            async_copy16(src + (size_t)ch * 16, dst + (size_t)ch * 16);
        }
    }

    // A fragments: 16 z rows per wave -> fp8 (16 VGPRs) + per-lane sum(z^2).
    // Lane holds A[m][k = q*8 + j]; k-block s covers dims s*32..+31.
    // NT loads: z is read exactly once per launch.
    long A8[8];
    float zsq = 0.f;
    {
        const float* zr = z + ((size_t)blockIdx.x * BM + wl * 16 + m) * D_DIM;
        #pragma unroll
        for (int s = 0; s < 8; s++) {
            const float* p = zr + s * 32 + q * 8;
            f4 v0 = __builtin_nontemporal_load((const f4*)p);
            f4 v1 = __builtin_nontemporal_load((const f4*)(p + 4));
            zsq += v0.x * v0.x + v0.y * v0.y + v0.z * v0.z + v0.w * v0.w
                 + v1.x * v1.x + v1.y * v1.y + v1.z * v1.z + v1.w * v1.w;
            A8[s] = pack_fp8x8(v0.x, v0.y, v0.z, v0.w, v1.x, v1.y, v1.z, v1.w);
        }
    }

    float best[4];
    int   bidx[4];
    #pragma unroll
    for (int r = 0; r < 4; r++) { best[r] = __builtin_inff(); bidx[r] = 0; }

    #pragma unroll 1
    for (int i = 0; i < NSLICE_G; i++) {
        // Barrier drains this wave's async loads (compiler emits vmcnt(0)
        // before s_barrier): sB[g][i&1] staged; sB[g][(i+1)&1] free.
        __syncthreads();

        if (i + 1 < NSLICE_G) {
            const char* src = emb8 + (size_t)(g * NSLICE_G + i + 1) * SLICE_BYTES;
            char* dst = sB[g][(i + 1) & 1];
            #pragma unroll
            for (int ii = 0; ii < 4; ii++) {
                int ch = ii * 256 + tidl;
                async_copy16(src + (size_t)ch * 16, dst + (size_t)ch * 16);
            }
        }

        const char* B = sB[g][i & 1];
        const int cbase = g * 512 + i * SLICE_CODES;
        float ete[4];
        #pragma unroll
        for (int ct = 0; ct < 4; ct++) ete[ct] = eTe[cbase + ct * 16 + m];

        f32x4 acc[4];
        #pragma unroll
        for (int ct = 0; ct < 4; ct++) acc[ct] = (f32x4){0.f, 0.f, 0.f, 0.f};

        // 4 t-steps: 4 ds_read_b128 feed 8 MFMAs; 4 indep chains/wave,
        // 4 waves/SIMD.
        #pragma unroll
        for (int t = 0; t < 4; t++) {
            l2 c0 = *(const l2*)(B + (size_t)((0 * 256) + t * 64 + lane) * 16);
            l2 c1 = *(const l2*)(B + (size_t)((1 * 256) + t * 64 + lane) * 16);
            l2 c2 = *(const l2*)(B + (size_t)((2 * 256) + t * 64 + lane) * 16);
            l2 c3 = *(const l2*)(B + (size_t)((3 * 256) + t * 64 + lane) * 16);
            acc[0] = __builtin_amdgcn_mfma_f32_16x16x32_fp8_fp8(A8[2*t],   c0.x, acc[0], 0, 0, 0);
            acc[1] = __builtin_amdgcn_mfma_f32_16x16x32_fp8_fp8(A8[2*t],   c1.x, acc[1], 0, 0, 0);
            acc[2] = __builtin_amdgcn_mfma_f32_16x16x32_fp8_fp8(A8[2*t],   c2.x, acc[2], 0, 0, 0);
            acc[3] = __builtin_amdgcn_mfma_f32_16x16x32_fp8_fp8(A8[2*t],   c3.x, acc[3], 0, 0, 0);
            acc[0] = __builtin_amdgcn_mfma_f32_16x16x32_fp8_fp8(A8[2*t+1], c0.y, acc[0], 0, 0, 0);
            acc[1] = __builtin_amdgcn_mfma_f32_16x16x32_fp8_fp8(A8[2*t+1], c1.y, acc[1], 0, 0, 0);
            acc[2] = __builtin_amdgcn_mfma_f32_16x16x32_fp8_fp8(A8[2*t+1], c2.y, acc[2], 0, 0, 0);
            acc[3] = __builtin_amdgcn_mfma_f32_16x16x32_fp8_fp8(A8[2*t+1], c3.y, acc[3], 0, 0, 0);
        }

        #pragma unroll
        for (int ct = 0; ct < 4; ct++) {
            int code = cbase + ct * 16 + m;
            #pragma unroll
            for (int r = 0; r < 4; r++) {
                float sc = fmaf(-2.0f, acc[ct][r], ete[ct]);
                if (sc < best[r]) { best[r] = sc; bidx[r] = code; }
            }
        }
    }

    // Cross-lane argmin over the 16 column-lanes; first-index tie-break.
    #pragma unroll
    for (int r = 0; r < 4; r++) {
        float b  = best[r];
        int   bi = bidx[r];
        #pragma unroll
        for (int off = 8; off >= 1; off >>= 1) {
            float ob = __shfl_xor(b, off);
            int   oi = __shfl_xor(bi, off);
            if (ob < b || (ob == b && oi < bi)) { b = ob; bi = oi; }
        }
        if (m == 0) {
            s_best[g][wl * 16 + q * 4 + r] = b;
            s_bidx[g][wl * 16 + q * 4 + r] = bi;
        }
    }
    __syncthreads();

    // Merge the two code-groups (group-0 indices < group-1: tie -> group 0).
    if (tid < BM) {
        float b0 = s_best[0][tid], b1 = s_best[1][tid];
        int   i0 = s_bidx[0][tid], i1 = s_bidx[1][tid];
        bool take1 = (b1 < b0);
        s_idx[tid] = take1 ? i1 : i0;
        s_fin[tid] = take1 ? b1 : b0;
    }
    __syncthreads();

    // Fused epilogue (group 0 only): out = emb[idx] (fp32, L2-hot) via NT
    // stores (out never re-read); loss_row = sum(z^2) + best_score/1024.
    float lsum = 0.f;
    if (g == 0) {
        int rl = wl * 16 + m;
        int idxv = s_idx[rl];
        const float* er = emb + (size_t)idxv * D_DIM;
        float* orow = out + ((size_t)blockIdx.x * BM + rl) * D_DIM;
        #pragma unroll
        for (int s = 0; s < 8; s++) {
            int dd = s * 32 + q * 8;
            f4 e0 = *(const f4*)(er + dd);
            f4 e1 = *(const f4*)(er + dd + 4);
            __builtin_nontemporal_store(e0, (f4*)(orow + dd));
            __builtin_nontemporal_store(e1, (f4*)(orow + dd + 4));
        }
        float zrow = zsq + __shfl_xor(zsq, 16);
        zrow += __shfl_xor(zrow, 32);
        if (q == 0) lsum = zrow + s_fin[rl] * (1.0f / 1024.0f);
        #pragma unroll
        for (int off = 32; off >= 1; off >>= 1) lsum += __shfl_down(lsum, off);
        if (lane == 0) s_red[wl] = lsum;
    }
    __syncthreads();
    if (tid == 0)
        atomicAdd(loss_slot, (s_red[0] + s_red[1] + s_red[2] + s_red[3]) * loss_scale);
}

// ---- Fallback (round-2 structure, verified) — only if ws too small. --------
__global__ __launch_bounds__(256) void vq_prep_fb(const float* __restrict__ emb,
                                                  float* __restrict__ eTe,
                                                  float* __restrict__ loss_slot) {
    if (blockIdx.x == 0 && threadIdx.x == 0) *loss_slot = 0.0f;
    if (!eTe) return;
    int gtid = blockIdx.x * 256 + threadIdx.x;
    int code = gtid >> 6;
    int lane = threadIdx.x & 63;
    if (code >= K_CODES) return;
    float4 v = ((const float4*)(emb + (size_t)code * D_DIM))[lane];
    float s = v.x * v.x + v.y * v.y + v.z * v.z + v.w * v.w;
    #pragma unroll
    for (int off = 32; off >= 1; off >>= 1) s += __shfl_down(s, off);
    if (lane == 0) eTe[code] = s;
}

__global__ __launch_bounds__(128) void vq_main_fb(const float* __restrict__ z,
                                                  const float* __restrict__ emb,
                                                  const float* __restrict__ eTe_g,
                                                  float* __restrict__ out,
                                                  float* __restrict__ loss_slot,
                                                  float loss_scale) {
    __shared__ __align__(16) f16 sE[128 * D_DIM];
    __shared__ float s_ete[128];
    __shared__ int   s_idx2[128];
    __shared__ float s_red2[2];

    const int tid  = threadIdx.x;
    const int wave = tid >> 6;
    const int lane = tid & 63;
    const int m    = lane & 15;
    const int q    = lane >> 4;
    const size_t row0 = (size_t)blockIdx.x * 128 + (size_t)wave * 64;

    f16x8 A[4][8];
    #pragma unroll
    for (int st = 0; st < 4; st++) {
        const float* zr = z + (row0 + st * 16 + m) * D_DIM;
        #pragma unroll
        for (int s = 0; s < 8; s++) {
            const float* p = zr + s * 32 + q * 8;
            float4 v0 = *(const float4*)p;
            float4 v1 = *(const float4*)(p + 4);
            f16x8 a = {(f16)v0.x, (f16)v0.y, (f16)v0.z, (f16)v0.w,
                       (f16)v1.x, (f16)v1.y, (f16)v1.z, (f16)v1.w};
            A[st][s] = a;
        }
    }
    float best[4][4]; int bidx[4][4];
    #pragma unroll
    for (int st = 0; st < 4; st++)
        #pragma unroll
        for (int r = 0; r < 4; r++) { best[st][r] = __builtin_inff(); bidx[st][r] = 0; }

    const f16x8* sE8 = (const f16x8*)sE;
    #pragma unroll 1
    for (int sp = 0; sp < 8; sp++) {
        __syncthreads();
        if (eTe_g) s_ete[tid] = 1024.0f * eTe_g[sp * 128 + tid];
        else {
            const float* p = emb + (size_t)(sp * 128 + tid) * D_DIM;
            float ss = 0.f;
            for (int j = 0; j < D_DIM / 4; j++) {
                float4 v = ((const float4*)p)[j];
                ss += v.x * v.x + v.y * v.y + v.z * v.z + v.w * v.w;
            }
            s_ete[tid] = 1024.0f * ss;
        }
        const float* ebase = emb + (size_t)sp * 128 * D_DIM;
        #pragma unroll 4
        for (int it = 0; it < 32; it++) {
            int ch = it * 128 + tid;
            int cc = ((ch >> 9) << 4) | (ch & 15);
            int gg = (ch >> 4) & 31;
            const float* p = ebase + cc * D_DIM + gg * 8;
            float4 v0 = *(const float4*)p;
            float4 v1 = *(const float4*)(p + 4);
            f16x8 h = {(f16)(v0.x * 1024.f), (f16)(v0.y * 1024.f),
                       (f16)(v0.z * 1024.f), (f16)(v0.w * 1024.f),
                       (f16)(v1.x * 1024.f), (f16)(v1.y * 1024.f),
                       (f16)(v1.z * 1024.f), (f16)(v1.w * 1024.f)};
            *(f16x8*)(sE + (size_t)ch * 8) = h;
        }
        __syncthreads();
        for (int ct = 0; ct < 8; ct++) {
            f32x4 acc[4];
            #pragma unroll
            for (int st = 0; st < 4; st++) acc[st] = (f32x4){0.f, 0.f, 0.f, 0.f};
            #pragma unroll
            for (int s = 0; s < 8; s++) {
                f16x8 bh = sE8[ct * 512 + s * 64 + lane];
                #pragma unroll
                for (int st = 0; st < 4; st++)
                    acc[st] = __builtin_amdgcn_mfma_f32_16x16x32_f16(A[st][s], bh, acc[st], 0, 0, 0);
            }
            int codeL = ct * 16 + m;
            float ete = s_ete[codeL];
            int code  = sp * 128 + codeL;
            #pragma unroll
            for (int st = 0; st < 4; st++)
                #pragma unroll
                for (int r = 0; r < 4; r++) {
                    float sc = fmaf(-2.0f, acc[st][r], ete);
                    if (sc < best[st][r]) { best[st][r] = sc; bidx[st][r] = code; }
                }
        }
    }
    #pragma unroll
    for (int st = 0; st < 4; st++)
        #pragma unroll
        for (int r = 0; r < 4; r++) {
            float b = best[st][r]; int bi = bidx[st][r];
            #pragma unroll
            for (int off = 8; off >= 1; off >>= 1) {
                float ob = __shfl_xor(b, off);
                int   oi = __shfl_xor(bi, off);
                if (ob < b || (ob == b && oi < bi)) { b = ob; bi = oi; }
            }
            if (m == 0) s_idx2[wave * 64 + st * 16 + q * 4 + r] = bi;
        }
    __syncthreads();
    float lsum = 0.f;
    #pragma unroll
    for (int st = 0; st < 4; st++) {
        int rl = wave * 64 + st * 16 + m;
        int idxv = s_idx2[rl];
        const float* er = emb + (size_t)idxv * D_DIM;
        float* orow = out + ((size_t)blockIdx.x * 128 + rl) * D_DIM;
        #pragma unroll
        for (int s = 0; s < 8; s++) {
            int dd = s * 32 + q * 8;
            float4 e0 = *(const float4*)(er + dd);
            float4 e1 = *(const float4*)(er + dd + 4);
            *(float4*)(orow + dd)     = e0;
            *(float4*)(orow + dd + 4) = e1;
            f16x8 a = A[st][s];
            float d0 = e0.x - (float)a[0], d1 = e0.y - (float)a[1];
            float d2 = e0.z - (float)a[2], d3 = e0.w - (float)a[3];
            float d4 = e1.x - (float)a[4], d5 = e1.y - (float)a[5];
            float d6 = e1.z - (float)a[6], d7 = e1.w - (float)a[7];
            lsum += d0*d0 + d1*d1 + d2*d2 + d3*d3 + d4*d4 + d5*d5 + d6*d6 + d7*d7;
        }
    }
    #pragma unroll
    for (int off = 32; off >= 1; off >>= 1) lsum += __shfl_down(lsum, off);
    if (lane == 0) s_red2[wave] = lsum;
    __syncthreads();
    if (tid == 0) atomicAdd(loss_slot, (s_red2[0] + s_red2[1]) * loss_scale);
}

extern "C" void kernel_launch(void* const* d_in, const int* in_sizes, int n_in,
                              void* d_out, int out_size, void* d_ws, size_t ws_size,
                              hipStream_t stream) {
    const float* z   = (const float*)d_in[0];
    const float* emb = (const float*)d_in[1];
    float* out = (float*)d_out;
    const int NROWS = in_sizes[0] / D_DIM;              // 32768
    float* loss_slot = out + (size_t)in_sizes[0];
    float loss_scale = 1.25f / (float)in_sizes[0];

    const size_t emb8_bytes = (size_t)K_CODES * D_DIM;  // 256 KB
    const size_t need = emb8_bytes + K_CODES * sizeof(float);

    if (ws_size >= need) {
        char*  emb8 = (char*)d_ws;
        float* eTe  = (float*)((char*)d_ws + emb8_bytes);
        vq_prep<<<256, 256, 0, stream>>>(emb, emb8, eTe, loss_slot);
        vq_main<<<NROWS / BM, 512, 0, stream>>>(z, emb8, eTe, emb, out, loss_slot, loss_scale);
    } else {
        float* eTe = (ws_size >= K_CODES * sizeof(float)) ? (float*)d_ws : nullptr;
        vq_prep_fb<<<K_CODES / 4, 256, 0, stream>>>(emb, eTe, loss_slot);
        vq_main_fb<<<NROWS / 128, 128, 0, stream>>>(z, emb, eTe, out, loss_slot, loss_scale);
    }
}